// Round 7
// baseline (435.267 us; speedup 1.0000x reference)
//
#include <hip/hip_runtime.h>
#include <cstddef>
#include <cstdint>

// GCN 3-layer forward, MI355X.
// R7: atomic-free CSC build. R6's decode_deg (75us, VALU 0.5%, HBM 10%) was
// bound by the memory-side atomic path (~21 atomics/ns; WRITE 56MB = 1.6M
// atomics x 32B write-through). Now: 64 blocks x private LDS histogram
// (u16-packed) -> hist[b][bin]; scan -> off; base[b][bin] prefix -> per-block
// LDS cursors for fill (LDS atomics only); deg/dinv + csr_val as segmented
// post-passes. Aggregation (bf16 gathers) and B-stationary MFMA GEMMs from R6.

#define GCN_BN_EPS 1e-5f
#define NB_HIST 64  // histogram/fill blocks (private LDS histograms)

typedef short v8bf __attribute__((ext_vector_type(8)));
typedef float v4f __attribute__((ext_vector_type(4)));

// ---------------------------------------------------------------- bf16 utils

__device__ __forceinline__ float4 unpack_bf4(uint2 u) {
  float4 r;
  r.x = __uint_as_float(u.x << 16);
  r.y = __uint_as_float(u.x & 0xffff0000u);
  r.z = __uint_as_float(u.y << 16);
  r.w = __uint_as_float(u.y & 0xffff0000u);
  return r;
}
__device__ __forceinline__ uint16_t f2bf(float f) {
  uint32_t u = __float_as_uint(f);
  return (uint16_t)((u + 0x7fffu + ((u >> 16) & 1u)) >> 16);  // RNE
}
__device__ __forceinline__ uint2 pack_bf4(float4 v) {
  uint2 r;
  r.x = (uint32_t)f2bf(v.x) | ((uint32_t)f2bf(v.y) << 16);
  r.y = (uint32_t)f2bf(v.z) | ((uint32_t)f2bf(v.w) << 16);
  return r;
}

// ---------------------------------------------------------------- preprocess

__global__ void detect_kernel(const int* __restrict__ ei, int* __restrict__ flag) {
  if (threadIdx.x == 0) {
    int nz = 0;
    for (int k = 1; k < 64; k += 2) nz |= ei[k];
    *flag = (nz == 0) ? 1 : 0;  // 1 => int64 layout (high dwords zero)
  }
}

// pure decode, no atomics
__global__ void decode_kernel(const int* __restrict__ ei, const int* __restrict__ flag,
                              int* __restrict__ row_, int* __restrict__ col_, int E) {
  int e = blockIdx.x * blockDim.x + threadIdx.x;
  if (e >= E) return;
  int r, c;
  if (*flag) { r = ei[2 * e]; c = ei[2 * (E + e)]; }
  else       { r = ei[e];     c = ei[E + e]; }
  row_[e] = r; col_[e] = c;
}

// per-block private LDS histogram (u16 packed, 2 bins/word) -> hist[b][bin]
__global__ __launch_bounds__(256) void hist_kernel(const int* __restrict__ col_,
                                                   int* __restrict__ hist,
                                                   int E, int n) {
  extern __shared__ unsigned int hsh[];  // (n+1)/2 words
  const int nw = (n + 1) >> 1;
  const int b = blockIdx.x;
  for (int i = threadIdx.x; i < nw; i += 256) hsh[i] = 0u;
  __syncthreads();
  const int per = (E + NB_HIST - 1) / NB_HIST;  // <= 65535 per block (u16 safe)
  const int e0 = b * per, e1 = min(e0 + per, E);
  for (int e = e0 + threadIdx.x; e < e1; e += 256) {
    int c = col_[e];
    atomicAdd(&hsh[c >> 1], 1u << ((c & 1) * 16));
  }
  __syncthreads();
  for (int i = threadIdx.x; i < n; i += 256)
    hist[(size_t)b * n + i] = (int)((hsh[i >> 1] >> ((i & 1) * 16)) & 0xffffu);
}

// scan phase 1: cnt[i] = sum_b hist[b][i]; per-256-block sums -> bsum
__global__ __launch_bounds__(256) void scan1_kernel(const int* __restrict__ hist,
                                                    int* __restrict__ cnt,
                                                    int* __restrict__ bsum, int n) {
  __shared__ int ws[4];
  int i = blockIdx.x * 256 + threadIdx.x;
  int v = 0;
  if (i < n) {
    for (int b = 0; b < NB_HIST; ++b) v += hist[(size_t)b * n + i];
    cnt[i] = v;
  }
  int x = v;
#pragma unroll
  for (int s = 1; s < 64; s <<= 1) x += __shfl_xor(x, s, 64);
  if ((threadIdx.x & 63) == 0) ws[threadIdx.x >> 6] = x;
  __syncthreads();
  if (threadIdx.x == 0) bsum[blockIdx.x] = ws[0] + ws[1] + ws[2] + ws[3];
}

__global__ __launch_bounds__(1024) void scan2_kernel(int* __restrict__ bsum, int G,
                                                     int* __restrict__ off, int n, int E) {
  __shared__ int wsum[16], woff[16];
  int tid = threadIdx.x, lane = tid & 63, wv = tid >> 6;
  int v = (tid < G) ? bsum[tid] : 0;
  int x = v;
#pragma unroll
  for (int s = 1; s < 64; s <<= 1) { int t = __shfl_up(x, s, 64); if (lane >= s) x += t; }
  if (lane == 63) wsum[wv] = x;
  __syncthreads();
  if (wv == 0) {
    int wsv = (lane < 16) ? wsum[lane] : 0;
    int y = wsv;
#pragma unroll
    for (int s = 1; s < 16; s <<= 1) { int t = __shfl_up(y, s, 64); if (lane >= s) y += t; }
    if (lane < 16) woff[lane] = y - wsv;
  }
  __syncthreads();
  if (tid < G) bsum[tid] = x - v + woff[wv];
  if (tid == 0) off[n] = E;
}

__global__ __launch_bounds__(256) void scan3_kernel(const int* __restrict__ cnt,
                                                    const int* __restrict__ bsum,
                                                    int* __restrict__ off, int n) {
  __shared__ int wsum[4], woff[4];
  int tid = threadIdx.x, lane = tid & 63, wv = tid >> 6;
  int i = blockIdx.x * 256 + tid;
  int v = (i < n) ? cnt[i] : 0;
  int x = v;
#pragma unroll
  for (int s = 1; s < 64; s <<= 1) { int t = __shfl_up(x, s, 64); if (lane >= s) x += t; }
  if (lane == 63) wsum[wv] = x;
  __syncthreads();
  if (tid == 0) { int r = 0; for (int k = 0; k < 4; ++k) { woff[k] = r; r += wsum[k]; } }
  __syncthreads();
  if (i < n) off[i] = x - v + woff[wv] + bsum[blockIdx.x];
}

// base[b][i] = off[i] + sum_{b'<b} hist[b'][i]   (in-place over hist)
__global__ void base_kernel(const int* __restrict__ off, int* __restrict__ hist, int n) {
  int i = blockIdx.x * blockDim.x + threadIdx.x;
  if (i >= n) return;
  int run = off[i];
  for (int b = 0; b < NB_HIST; ++b) {
    size_t idx = (size_t)b * n + i;
    int h = hist[idx];
    hist[idx] = run;
    run += h;
  }
}

// fill via per-block LDS cursors (two half-range passes); zero global atomics
__global__ __launch_bounds__(256) void fill_kernel(
    const int* __restrict__ row_, const int* __restrict__ col_,
    const float* __restrict__ ew, const int* __restrict__ base,
    int* __restrict__ csr_src, float* __restrict__ csr_w, int E, int n) {
  extern __shared__ int cur[];  // (n+1)/2 cursors
  const int nh = (n + 1) >> 1;
  const int b = blockIdx.x;
  const int per = (E + NB_HIST - 1) / NB_HIST;
  const int e0 = b * per, e1 = min(e0 + per, E);
  for (int half = 0; half < 2; ++half) {
    const int lo = half * nh;
    const int hi = min(lo + nh, n);
    for (int i = threadIdx.x; i < hi - lo; i += 256)
      cur[i] = base[(size_t)b * n + lo + i];
    __syncthreads();
    for (int e = e0 + threadIdx.x; e < e1; e += 256) {
      int c = col_[e];
      if (c >= lo && c < hi) {
        int p = atomicAdd(&cur[c - lo], 1);
        csr_src[p] = row_[e];
        csr_w[p] = ew[e];
      }
    }
    __syncthreads();
  }
}

// deg = 1 + segment-sum of weights; dinv = rsqrt(deg)
__global__ void degdinv_kernel(const int* __restrict__ off, const float* __restrict__ csr_w,
                               float* __restrict__ dinv, int n) {
  int i = blockIdx.x * blockDim.x + threadIdx.x;
  if (i >= n) return;
  float s = 1.0f;
  int p1 = off[i + 1];
  for (int p = off[i]; p < p1; ++p) s += csr_w[p];
  dinv[i] = rsqrtf(s);
}

// csr_val[p] = dinv[src] * w * dinv[c]
__global__ void val_kernel(const int* __restrict__ off, const int* __restrict__ csr_src,
                           const float* __restrict__ csr_w, const float* __restrict__ dinv,
                           float* __restrict__ csr_val, int n) {
  int i = blockIdx.x * blockDim.x + threadIdx.x;
  if (i >= n) return;
  float dc = dinv[i];
  int p1 = off[i + 1];
  for (int p = off[i]; p < p1; ++p)
    csr_val[p] = dinv[csr_src[p]] * csr_w[p] * dc;
}

// ---------------------------------------------------------------- conversions

__global__ void conv_x_kernel(const float* __restrict__ x, uint16_t* __restrict__ xb,
                              int n4) {
  int i = blockIdx.x * blockDim.x + threadIdx.x;
  if (i >= n4) return;
  float4 v = *(const float4*)&x[(size_t)i * 4];
  *(uint2*)&xb[(size_t)i * 4] = pack_bf4(v);
}

// W[K][N] fp32 -> WT[N][K] bf16
__global__ void conv_wt_kernel(const float* __restrict__ W, uint16_t* __restrict__ WT,
                               int K, int Nc) {
  int i = blockIdx.x * blockDim.x + threadIdx.x;
  if (i >= K * Nc) return;
  int n = i / K, k = i - n * K;
  WT[i] = f2bf(W[(size_t)k * Nc + n]);
}

// ---------------------------------------------------------------- aggregation

// D=256 bf16: one wave per node, lane holds 4 feats (8B). EPI 0 plain, 1 BN+ReLU
template <int EPI>
__global__ __launch_bounds__(256) void agg256_kernel(
    const uint16_t* __restrict__ hin, uint16_t* __restrict__ hout,
    const int* __restrict__ off, const int* __restrict__ src,
    const float* __restrict__ val, const float* __restrict__ dinv,
    const float* __restrict__ bias, const float* __restrict__ g,
    const float* __restrict__ be, int n) {
  const int lane = threadIdx.x & 63;
  const int c = blockIdx.x * 4 + (threadIdx.x >> 6);
  if (c >= n) return;
  const int f = lane * 4;
  const int e0 = off[c], e1 = off[c + 1];
  const float di = dinv[c];
  const float s2 = di * di;
  float4 self = unpack_bf4(*(const uint2*)&hin[(size_t)c * 256 + f]);
  float4 acc = make_float4(self.x * s2, self.y * s2, self.z * s2, self.w * s2);

  for (int base = e0; base < e1; base += 64) {
    int idx = base + lane;
    int rs = 0; float rv = 0.0f;                 // zero-pad: row 0 x weight 0
    if (idx < e1) { rs = src[idx]; rv = val[idx]; }
    const int m = min(64, e1 - base);
    const int nG = (m + 3) >> 2;
    for (int gI = 0; gI < nG; ++gI) {
      int e_ = gI * 4;
      int s0 = __shfl(rs, e_);     float v0 = __shfl(rv, e_);
      int s1 = __shfl(rs, e_ + 1); float v1 = __shfl(rv, e_ + 1);
      int sB = __shfl(rs, e_ + 2); float v2 = __shfl(rv, e_ + 2);
      int s3 = __shfl(rs, e_ + 3); float v3 = __shfl(rv, e_ + 3);
      float4 h0 = unpack_bf4(*(const uint2*)&hin[(size_t)s0 * 256 + f]);
      float4 h1 = unpack_bf4(*(const uint2*)&hin[(size_t)s1 * 256 + f]);
      float4 h2 = unpack_bf4(*(const uint2*)&hin[(size_t)sB * 256 + f]);
      float4 h3 = unpack_bf4(*(const uint2*)&hin[(size_t)s3 * 256 + f]);
      acc.x += v0 * h0.x + v1 * h1.x + v2 * h2.x + v3 * h3.x;
      acc.y += v0 * h0.y + v1 * h1.y + v2 * h2.y + v3 * h3.y;
      acc.z += v0 * h0.z + v1 * h1.z + v2 * h2.z + v3 * h3.z;
      acc.w += v0 * h0.w + v1 * h1.w + v2 * h2.w + v3 * h3.w;
    }
  }

  if (EPI == 1) {
    const float bns = rsqrtf(1.0f + GCN_BN_EPS);
    float4 bi = *(const float4*)&bias[f];
    float4 gi = *(const float4*)&g[f];
    float4 bei = *(const float4*)&be[f];
    acc.x = fmaxf((acc.x + bi.x) * gi.x * bns + bei.x, 0.0f);
    acc.y = fmaxf((acc.y + bi.y) * gi.y * bns + bei.y, 0.0f);
    acc.z = fmaxf((acc.z + bi.z) * gi.z * bns + bei.z, 0.0f);
    acc.w = fmaxf((acc.w + bi.w) * gi.w * bns + bei.w, 0.0f);
  }
  *(uint2*)&hout[(size_t)c * 256 + f] = pack_bf4(acc);
}

// D=128 bf16: two nodes per wave (half-wave x 4 feats, 8B/lane).
// EPI 0: plain bf16 store. EPI 2: +bias, log_softmax -> fp32 out.
template <int EPI>
__global__ __launch_bounds__(256) void agg128_kernel(
    const uint16_t* __restrict__ hin, void* __restrict__ hout_,
    const int* __restrict__ off, const int* __restrict__ src,
    const float* __restrict__ val, const float* __restrict__ dinv,
    const float* __restrict__ bias, int n) {
  const int lane = threadIdx.x & 63;
  const int sub = lane & 31;
  const int hbase = lane & 32;
  const int c = blockIdx.x * 8 + (threadIdx.x >> 6) * 2 + (lane >> 5);
  const bool active = (c < n);
  const int f = sub * 4;

  int e0 = 0, e1 = 0;
  float4 acc = make_float4(0.f, 0.f, 0.f, 0.f);
  if (active) {
    e0 = off[c]; e1 = off[c + 1];
    float di = dinv[c];
    float s2 = di * di;
    float4 self = unpack_bf4(*(const uint2*)&hin[(size_t)c * 128 + f]);
    acc = make_float4(self.x * s2, self.y * s2, self.z * s2, self.w * s2);
  }
  int nch = (e1 - e0 + 31) >> 5;
  nch = max(nch, __shfl(nch, lane ^ 32));

  for (int ch = 0; ch < nch; ++ch) {
    int idx = e0 + ch * 32 + sub;
    int rs = 0; float rv = 0.0f;
    if (active && idx < e1) { rs = src[idx]; rv = val[idx]; }
    int m = e1 - (e0 + ch * 32);
    m = m < 0 ? 0 : (m > 32 ? 32 : m);
    int mMax = max(m, __shfl(m, lane ^ 32));
    const int nG = (mMax + 3) >> 2;
    for (int gI = 0; gI < nG; ++gI) {
      int e_ = hbase + gI * 4;
      int s0 = __shfl(rs, e_);     float v0 = __shfl(rv, e_);
      int s1 = __shfl(rs, e_ + 1); float v1 = __shfl(rv, e_ + 1);
      int sB = __shfl(rs, e_ + 2); float v2 = __shfl(rv, e_ + 2);
      int s3 = __shfl(rs, e_ + 3); float v3 = __shfl(rv, e_ + 3);
      float4 h0 = unpack_bf4(*(const uint2*)&hin[(size_t)s0 * 128 + f]);
      float4 h1 = unpack_bf4(*(const uint2*)&hin[(size_t)s1 * 128 + f]);
      float4 h2 = unpack_bf4(*(const uint2*)&hin[(size_t)sB * 128 + f]);
      float4 h3 = unpack_bf4(*(const uint2*)&hin[(size_t)s3 * 128 + f]);
      acc.x += v0 * h0.x + v1 * h1.x + v2 * h2.x + v3 * h3.x;
      acc.y += v0 * h0.y + v1 * h1.y + v2 * h2.y + v3 * h3.y;
      acc.z += v0 * h0.z + v1 * h1.z + v2 * h2.z + v3 * h3.z;
      acc.w += v0 * h0.w + v1 * h1.w + v2 * h2.w + v3 * h3.w;
    }
  }

  if (EPI == 0) {
    uint16_t* hout = (uint16_t*)hout_;
    if (active) *(uint2*)&hout[(size_t)c * 128 + f] = pack_bf4(acc);
  } else {
    float* hout = (float*)hout_;
    float4 bi = active ? *(const float4*)&bias[f] : make_float4(0.f, 0.f, 0.f, 0.f);
    float tx = acc.x + bi.x, ty = acc.y + bi.y, tz = acc.z + bi.z, tw = acc.w + bi.w;
    float mx = fmaxf(fmaxf(tx, ty), fmaxf(tz, tw));
#pragma unroll
    for (int s = 1; s < 32; s <<= 1) mx = fmaxf(mx, __shfl_xor(mx, s, 64));
    float ex = expf(tx - mx) + expf(ty - mx) + expf(tz - mx) + expf(tw - mx);
#pragma unroll
    for (int s = 1; s < 32; s <<= 1) ex += __shfl_xor(ex, s, 64);
    float lse = logf(ex) + mx;
    if (active) {
      float4 res = make_float4(tx - lse, ty - lse, tz - lse, tw - lse);
      *(float4*)&hout[(size_t)c * 128 + f] = res;
    }
  }
}

// ---------------------------------------------------------------- MFMA GEMM
// B-stationary: wave holds B-frags for its col group across all K in registers,
// streams 16-row A-tiles with depth-2 prefetch; 4 waves/block share A rows.
template <int K, int NC, int EPI>
__global__ __launch_bounds__(256) void mfma_gemm_kernel(
    const uint16_t* __restrict__ A, const uint16_t* __restrict__ WT,
    uint16_t* __restrict__ Cb, int M, int tpb,
    const float* __restrict__ bias, const float* __restrict__ g,
    const float* __restrict__ be) {
  constexpr int CW = NC / 4;
  constexpr int NT = CW / 16;
  constexpr int KS = K / 32;
  const int lane = threadIdx.x & 63;
  const int wave = threadIdx.x >> 6;
  const int quad = lane >> 4;
  const int l16 = lane & 15;
  const int col0 = wave * CW;

  const int tiles = (M + 15) >> 4;
  int t0 = blockIdx.x * tpb;
  if (t0 >= tiles) return;
  int t1 = min(t0 + tpb, tiles);

  v8bf b[KS][NT];
#pragma unroll
  for (int ks = 0; ks < KS; ++ks)
#pragma unroll
    for (int nt = 0; nt < NT; ++nt)
      b[ks][nt] = *(const v8bf*)(WT + (size_t)(col0 + nt * 16 + l16) * K +
                                 ks * 32 + quad * 8);

  float sc[NT], o1[NT], o2[NT];
  if (EPI == 1) {
    const float bns = rsqrtf(1.0f + GCN_BN_EPS);
#pragma unroll
    for (int nt = 0; nt < NT; ++nt) {
      int col = col0 + nt * 16 + l16;
      sc[nt] = g[col] * bns; o1[nt] = bias[col]; o2[nt] = be[col];
    }
  }

  v8bf a[KS], an[KS];
  {
    int arow = min(t0 * 16 + l16, M - 1);
    const uint16_t* Ap = A + (size_t)arow * K + quad * 8;
#pragma unroll
    for (int ks = 0; ks < KS; ++ks) a[ks] = *(const v8bf*)(Ap + ks * 32);
  }
  for (int t = t0; t < t1; ++t) {
    if (t + 1 < t1) {
      int arow = min((t + 1) * 16 + l16, M - 1);
      const uint16_t* Ap = A + (size_t)arow * K + quad * 8;
#pragma unroll
      for (int ks = 0; ks < KS; ++ks) an[ks] = *(const v8bf*)(Ap + ks * 32);
    }
    v4f acc[NT];
#pragma unroll
    for (int nt = 0; nt < NT; ++nt) acc[nt] = (v4f){0.f, 0.f, 0.f, 0.f};
#pragma unroll
    for (int ks = 0; ks < KS; ++ks)
#pragma unroll
      for (int nt = 0; nt < NT; ++nt)
        acc[nt] = __builtin_amdgcn_mfma_f32_16x16x32_bf16(a[ks], b[ks][nt],
                                                          acc[nt], 0, 0, 0);
    const int row0 = t * 16 + quad * 4;
#pragma unroll
    for (int nt = 0; nt < NT; ++nt) {
      const int col = col0 + nt * 16 + l16;
#pragma unroll
      for (int r = 0; r < 4; ++r) {
        int row = row0 + r;
        if (row < M) {
          float v = acc[nt][r];
          if (EPI == 1) v = fmaxf((v + o1[nt]) * sc[nt] + o2[nt], 0.0f);
          Cb[(size_t)row * NC + col] = f2bf(v);
        }
      }
    }
#pragma unroll
    for (int ks = 0; ks < KS; ++ks) a[ks] = an[ks];
  }
}

// ---------------------------------------------------------------- launch

static inline char* carve(char*& p, size_t bytes) {
  char* r = p;
  p += (bytes + 255) & ~(size_t)255;
  return r;
}

extern "C" void kernel_launch(void* const* d_in, const int* in_sizes, int n_in,
                              void* d_out, int out_size, void* d_ws, size_t ws_size,
                              hipStream_t stream) {
  const int N = in_sizes[0] / 128;
  const int E = in_sizes[2];

  const float* x  = (const float*)d_in[0];
  const int*   ei = (const int*)d_in[1];
  const float* ew = (const float*)d_in[2];
  const float* W0 = (const float*)d_in[3];
  const float* b0 = (const float*)d_in[4];
  const float* W1 = (const float*)d_in[5];
  const float* b1 = (const float*)d_in[6];
  const float* Wl = (const float*)d_in[7];
  const float* bl = (const float*)d_in[8];
  const float* g0 = (const float*)d_in[9];
  const float* be0 = (const float*)d_in[10];
  const float* g1 = (const float*)d_in[11];
  const float* be1 = (const float*)d_in[12];
  float* out = (float*)d_out;

  char* p = (char*)d_ws;
  float*    dinv    = (float*)carve(p, (size_t)N * 4);
  int*      cnt     = (int*)carve(p, (size_t)N * 4);
  int*      off     = (int*)carve(p, (size_t)(N + 1) * 4);
  int*      flag    = (int*)carve(p, 256);
  int*      bsum    = (int*)carve(p, 1024 * 4);
  int*      row_    = (int*)carve(p, (size_t)E * 4);
  int*      col_    = (int*)carve(p, (size_t)E * 4);
  int*      csr_src = (int*)carve(p, (size_t)E * 4);
  float*    csr_w   = (float*)carve(p, (size_t)E * 4);
  float*    csr_val = (float*)carve(p, (size_t)E * 4);
  int*      hist    = (int*)carve(p, (size_t)NB_HIST * N * 4);  // becomes base
  uint16_t* xb16    = (uint16_t*)carve(p, (size_t)N * 128 * 2);
  uint16_t* bufR    = (uint16_t*)carve(p, (size_t)N * 128 * 2);
  uint16_t* bufP    = (uint16_t*)carve(p, (size_t)N * 256 * 2);
  uint16_t* bufQ    = (uint16_t*)carve(p, (size_t)N * 256 * 2);
  uint16_t* W0t     = (uint16_t*)carve(p, (size_t)128 * 256 * 2);
  uint16_t* W1t     = (uint16_t*)carve(p, (size_t)256 * 256 * 2);
  uint16_t* Wlt     = (uint16_t*)carve(p, (size_t)256 * 128 * 2);

  const int TB = 256;
  const int gN = (N + TB - 1) / TB;
  const int gE = (E + TB - 1) / TB;
  const int gW4 = (N + 3) / 4;
  const int gW8 = (N + 7) / 8;
  const int tiles = (N + 15) / 16;
  const int TPB = 4;
  const int gG = (tiles + TPB - 1) / TPB;
  const size_t ldsHist = (size_t)((N + 1) / 2) * 4;  // 100KB for N=50k

  // CSC build (zero global atomics)
  detect_kernel<<<1, 64, 0, stream>>>(ei, flag);
  decode_kernel<<<gE, TB, 0, stream>>>(ei, flag, row_, col_, E);
  hist_kernel<<<NB_HIST, TB, ldsHist, stream>>>(col_, hist, E, N);
  scan1_kernel<<<gN, TB, 0, stream>>>(hist, cnt, bsum, N);
  scan2_kernel<<<1, 1024, 0, stream>>>(bsum, gN, off, N, E);
  scan3_kernel<<<gN, TB, 0, stream>>>(cnt, bsum, off, N);
  base_kernel<<<gN, TB, 0, stream>>>(off, hist, N);
  fill_kernel<<<NB_HIST, TB, ldsHist, stream>>>(row_, col_, ew, hist,
                                                csr_src, csr_w, E, N);
  degdinv_kernel<<<gN, TB, 0, stream>>>(off, csr_w, dinv, N);
  val_kernel<<<gN, TB, 0, stream>>>(off, csr_src, csr_w, dinv, csr_val, N);

  // conversions
  conv_x_kernel<<<(N * 32 + TB - 1) / TB, TB, 0, stream>>>(x, xb16, N * 32);
  conv_wt_kernel<<<(128 * 256 + TB - 1) / TB, TB, 0, stream>>>(W0, W0t, 128, 256);
  conv_wt_kernel<<<(256 * 256 + TB - 1) / TB, TB, 0, stream>>>(W1, W1t, 256, 256);
  conv_wt_kernel<<<(256 * 128 + TB - 1) / TB, TB, 0, stream>>>(Wl, Wlt, 256, 128);

  // layer 0: agg(xb16,128) -> bufR; MFMA GEMM0 +BN0+ReLU -> bufP[N,256]
  agg128_kernel<0><<<gW8, 256, 0, stream>>>(xb16, bufR, off, csr_src, csr_val, dinv,
                                            nullptr, N);
  mfma_gemm_kernel<128, 256, 1><<<gG, 256, 0, stream>>>(bufR, W0t, bufP, N, TPB,
                                                        b0, g0, be0);
  // layer 1: GEMM1 -> bufQ; agg256 +b1+BN1+ReLU -> bufP
  mfma_gemm_kernel<256, 256, 0><<<gG, 256, 0, stream>>>(bufP, W1t, bufQ, N, TPB,
                                                        nullptr, nullptr, nullptr);
  agg256_kernel<1><<<gW4, 256, 0, stream>>>(bufQ, bufP, off, csr_src, csr_val, dinv,
                                            b1, g1, be1, N);
  // layer 2: GEMM2 -> bufR; agg128 +bl+log_softmax -> out (fp32)
  mfma_gemm_kernel<256, 128, 0><<<gG, 256, 0, stream>>>(bufP, Wlt, bufR, N, TPB,
                                                        nullptr, nullptr, nullptr);
  agg128_kernel<2><<<gW8, 256, 0, stream>>>(bufR, out, off, csr_src, csr_val, dinv,
                                            bl, N);
}

// Round 8
// 399.980 us; speedup vs baseline: 1.0882x; 1.0882x over previous
//
#include <hip/hip_runtime.h>
#include <cstddef>
#include <cstdint>

// GCN 3-layer forward, MI355X.
// R8: CSC build re-parallelized. R7's fill (80us) had 64 blocks x 100KB LDS ->
// 2.5% occupancy, latency-serialized; and 2 scattered 4B stores/edge (54MB
// write-amp). Now: grid (64 edge-chunks x 4 node-parts), 25/50KB LDS, and
// (src,w) packed in one uint2 -> single 8B scattered store per edge. Agg reads
// (src,val) as one uint2. Agg (bf16) + B-stationary MFMA GEMMs from R6/R7.

#define GCN_BN_EPS 1e-5f
#define NB_CHUNK 64  // edge chunks (u16 hist safe: E/64 = 12.5k < 65535)
#define NPART 4      // node-range parts

typedef short v8bf __attribute__((ext_vector_type(8)));
typedef float v4f __attribute__((ext_vector_type(4)));

// ---------------------------------------------------------------- bf16 utils

__device__ __forceinline__ float4 unpack_bf4(uint2 u) {
  float4 r;
  r.x = __uint_as_float(u.x << 16);
  r.y = __uint_as_float(u.x & 0xffff0000u);
  r.z = __uint_as_float(u.y << 16);
  r.w = __uint_as_float(u.y & 0xffff0000u);
  return r;
}
__device__ __forceinline__ uint16_t f2bf(float f) {
  uint32_t u = __float_as_uint(f);
  return (uint16_t)((u + 0x7fffu + ((u >> 16) & 1u)) >> 16);  // RNE
}
__device__ __forceinline__ uint2 pack_bf4(float4 v) {
  uint2 r;
  r.x = (uint32_t)f2bf(v.x) | ((uint32_t)f2bf(v.y) << 16);
  r.y = (uint32_t)f2bf(v.z) | ((uint32_t)f2bf(v.w) << 16);
  return r;
}

// ---------------------------------------------------------------- preprocess

__global__ void detect_kernel(const int* __restrict__ ei, int* __restrict__ flag) {
  if (threadIdx.x == 0) {
    int nz = 0;
    for (int k = 1; k < 64; k += 2) nz |= ei[k];
    *flag = (nz == 0) ? 1 : 0;  // 1 => int64 layout (high dwords zero)
  }
}

// decode: col_[e]; pk[e] = (src, w-bits) packed uint2
__global__ void decode_kernel(const int* __restrict__ ei, const float* __restrict__ ew,
                              const int* __restrict__ flag,
                              int* __restrict__ col_, uint2* __restrict__ pk, int E) {
  int e = blockIdx.x * blockDim.x + threadIdx.x;
  if (e >= E) return;
  int r, c;
  if (*flag) { r = ei[2 * e]; c = ei[2 * (E + e)]; }
  else       { r = ei[e];     c = ei[E + e]; }
  col_[e] = c;
  pk[e] = make_uint2((unsigned)r, __float_as_uint(ew[e]));
}

// per (chunk, part): private LDS histogram (u16 packed) of this node part
__global__ __launch_bounds__(256) void hist_kernel(const int* __restrict__ col_,
                                                   int* __restrict__ hist,
                                                   int E, int n) {
  extern __shared__ unsigned int hsh[];
  const int chunk = blockIdx.x, part = blockIdx.y;
  const int npl = (n + NPART - 1) / NPART;
  const int lo = part * npl, hi = min(lo + npl, n);
  const int nw = (npl + 1) >> 1;
  for (int i = threadIdx.x; i < nw; i += 256) hsh[i] = 0u;
  __syncthreads();
  const int per = (E + NB_CHUNK - 1) / NB_CHUNK;
  const int e0 = chunk * per, e1 = min(e0 + per, E);
  for (int e = e0 + threadIdx.x; e < e1; e += 256) {
    int c = col_[e];
    if (c >= lo && c < hi) {
      int cl = c - lo;
      atomicAdd(&hsh[cl >> 1], 1u << ((cl & 1) * 16));
    }
  }
  __syncthreads();
  for (int i = threadIdx.x; i < hi - lo; i += 256)
    hist[(size_t)chunk * n + lo + i] = (int)((hsh[i >> 1] >> ((i & 1) * 16)) & 0xffffu);
}

// scan phase 1: cnt[i] = sum_chunk hist[chunk][i]; per-256-block sums -> bsum
__global__ __launch_bounds__(256) void scan1_kernel(const int* __restrict__ hist,
                                                    int* __restrict__ cnt,
                                                    int* __restrict__ bsum, int n) {
  __shared__ int ws[4];
  int i = blockIdx.x * 256 + threadIdx.x;
  int v = 0;
  if (i < n) {
    for (int b = 0; b < NB_CHUNK; ++b) v += hist[(size_t)b * n + i];
    cnt[i] = v;
  }
  int x = v;
#pragma unroll
  for (int s = 1; s < 64; s <<= 1) x += __shfl_xor(x, s, 64);
  if ((threadIdx.x & 63) == 0) ws[threadIdx.x >> 6] = x;
  __syncthreads();
  if (threadIdx.x == 0) bsum[blockIdx.x] = ws[0] + ws[1] + ws[2] + ws[3];
}

__global__ __launch_bounds__(1024) void scan2_kernel(int* __restrict__ bsum, int G,
                                                     int* __restrict__ off, int n, int E) {
  __shared__ int wsum[16], woff[16];
  int tid = threadIdx.x, lane = tid & 63, wv = tid >> 6;
  int v = (tid < G) ? bsum[tid] : 0;
  int x = v;
#pragma unroll
  for (int s = 1; s < 64; s <<= 1) { int t = __shfl_up(x, s, 64); if (lane >= s) x += t; }
  if (lane == 63) wsum[wv] = x;
  __syncthreads();
  if (wv == 0) {
    int wsv = (lane < 16) ? wsum[lane] : 0;
    int y = wsv;
#pragma unroll
    for (int s = 1; s < 16; s <<= 1) { int t = __shfl_up(y, s, 64); if (lane >= s) y += t; }
    if (lane < 16) woff[lane] = y - wsv;
  }
  __syncthreads();
  if (tid < G) bsum[tid] = x - v + woff[wv];
  if (tid == 0) off[n] = E;
}

__global__ __launch_bounds__(256) void scan3_kernel(const int* __restrict__ cnt,
                                                    const int* __restrict__ bsum,
                                                    int* __restrict__ off, int n) {
  __shared__ int wsum[4], woff[4];
  int tid = threadIdx.x, lane = tid & 63, wv = tid >> 6;
  int i = blockIdx.x * 256 + tid;
  int v = (i < n) ? cnt[i] : 0;
  int x = v;
#pragma unroll
  for (int s = 1; s < 64; s <<= 1) { int t = __shfl_up(x, s, 64); if (lane >= s) x += t; }
  if (lane == 63) wsum[wv] = x;
  __syncthreads();
  if (tid == 0) { int r = 0; for (int k = 0; k < 4; ++k) { woff[k] = r; r += wsum[k]; } }
  __syncthreads();
  if (i < n) off[i] = x - v + woff[wv] + bsum[blockIdx.x];
}

// base[b][i] = off[i] + sum_{b'<b} hist[b'][i]   (in-place over hist)
__global__ void base_kernel(const int* __restrict__ off, int* __restrict__ hist, int n) {
  int i = blockIdx.x * blockDim.x + threadIdx.x;
  if (i >= n) return;
  int run = off[i];
  for (int b = 0; b < NB_CHUNK; ++b) {
    size_t idx = (size_t)b * n + i;
    int h = hist[idx];
    hist[idx] = run;
    run += h;
  }
}

// fill: per (chunk, part) LDS cursors; single 8B packed store per edge
__global__ __launch_bounds__(256) void fill_kernel(
    const int* __restrict__ col_, const uint2* __restrict__ pk,
    const int* __restrict__ base, uint2* __restrict__ csr, int E, int n) {
  extern __shared__ int cur[];
  const int chunk = blockIdx.x, part = blockIdx.y;
  const int npl = (n + NPART - 1) / NPART;
  const int lo = part * npl, hi = min(lo + npl, n);
  for (int i = threadIdx.x; i < hi - lo; i += 256)
    cur[i] = base[(size_t)chunk * n + lo + i];
  __syncthreads();
  const int per = (E + NB_CHUNK - 1) / NB_CHUNK;
  const int e0 = chunk * per, e1 = min(e0 + per, E);
  for (int e = e0 + threadIdx.x; e < e1; e += 256) {
    int c = col_[e];
    if (c >= lo && c < hi) {
      int p = atomicAdd(&cur[c - lo], 1);
      csr[p] = pk[e];
    }
  }
}

// deg = 1 + segment-sum of weights; dinv = rsqrt(deg)
__global__ void degdinv_kernel(const int* __restrict__ off, const uint2* __restrict__ csr,
                               float* __restrict__ dinv, int n) {
  int i = blockIdx.x * blockDim.x + threadIdx.x;
  if (i >= n) return;
  float s = 1.0f;
  int p1 = off[i + 1];
  for (int p = off[i]; p < p1; ++p) s += __uint_as_float(csr[p].y);
  dinv[i] = rsqrtf(s);
}

// csr[p].y: w -> dinv[src] * w * dinv[c]   (in place)
__global__ void val_kernel(const int* __restrict__ off, uint2* __restrict__ csr,
                           const float* __restrict__ dinv, int n) {
  int i = blockIdx.x * blockDim.x + threadIdx.x;
  if (i >= n) return;
  float dc = dinv[i];
  int p1 = off[i + 1];
  for (int p = off[i]; p < p1; ++p) {
    uint2 t = csr[p];
    csr[p].y = __float_as_uint(dinv[t.x] * __uint_as_float(t.y) * dc);
  }
}

// ---------------------------------------------------------------- conversions

__global__ void conv_x_kernel(const float* __restrict__ x, uint16_t* __restrict__ xb,
                              int n4) {
  int i = blockIdx.x * blockDim.x + threadIdx.x;
  if (i >= n4) return;
  float4 v = *(const float4*)&x[(size_t)i * 4];
  *(uint2*)&xb[(size_t)i * 4] = pack_bf4(v);
}

// W[K][N] fp32 -> WT[N][K] bf16
__global__ void conv_wt_kernel(const float* __restrict__ W, uint16_t* __restrict__ WT,
                               int K, int Nc) {
  int i = blockIdx.x * blockDim.x + threadIdx.x;
  if (i >= K * Nc) return;
  int n = i / K, k = i - n * K;
  WT[i] = f2bf(W[(size_t)k * Nc + n]);
}

// ---------------------------------------------------------------- aggregation
// csr[p] = (src, val-bits): one uint2 gather per edge slot.

// D=256 bf16: one wave per node, lane holds 4 feats (8B). EPI 0 plain, 1 BN+ReLU
template <int EPI>
__global__ __launch_bounds__(256) void agg256_kernel(
    const uint16_t* __restrict__ hin, uint16_t* __restrict__ hout,
    const int* __restrict__ off, const uint2* __restrict__ csr,
    const float* __restrict__ dinv,
    const float* __restrict__ bias, const float* __restrict__ g,
    const float* __restrict__ be, int n) {
  const int lane = threadIdx.x & 63;
  const int c = blockIdx.x * 4 + (threadIdx.x >> 6);
  if (c >= n) return;
  const int f = lane * 4;
  const int e0 = off[c], e1 = off[c + 1];
  const float di = dinv[c];
  const float s2 = di * di;
  float4 self = unpack_bf4(*(const uint2*)&hin[(size_t)c * 256 + f]);
  float4 acc = make_float4(self.x * s2, self.y * s2, self.z * s2, self.w * s2);

  for (int base = e0; base < e1; base += 64) {
    int idx = base + lane;
    int rs = 0; float rv = 0.0f;                 // zero-pad: row 0 x weight 0
    if (idx < e1) { uint2 ev = csr[idx]; rs = (int)ev.x; rv = __uint_as_float(ev.y); }
    const int m = min(64, e1 - base);
    const int nG = (m + 3) >> 2;
    for (int gI = 0; gI < nG; ++gI) {
      int e_ = gI * 4;
      int s0 = __shfl(rs, e_);     float v0 = __shfl(rv, e_);
      int s1 = __shfl(rs, e_ + 1); float v1 = __shfl(rv, e_ + 1);
      int sB = __shfl(rs, e_ + 2); float v2 = __shfl(rv, e_ + 2);
      int s3 = __shfl(rs, e_ + 3); float v3 = __shfl(rv, e_ + 3);
      float4 h0 = unpack_bf4(*(const uint2*)&hin[(size_t)s0 * 256 + f]);
      float4 h1 = unpack_bf4(*(const uint2*)&hin[(size_t)s1 * 256 + f]);
      float4 h2 = unpack_bf4(*(const uint2*)&hin[(size_t)sB * 256 + f]);
      float4 h3 = unpack_bf4(*(const uint2*)&hin[(size_t)s3 * 256 + f]);
      acc.x += v0 * h0.x + v1 * h1.x + v2 * h2.x + v3 * h3.x;
      acc.y += v0 * h0.y + v1 * h1.y + v2 * h2.y + v3 * h3.y;
      acc.z += v0 * h0.z + v1 * h1.z + v2 * h2.z + v3 * h3.z;
      acc.w += v0 * h0.w + v1 * h1.w + v2 * h2.w + v3 * h3.w;
    }
  }

  if (EPI == 1) {
    const float bns = rsqrtf(1.0f + GCN_BN_EPS);
    float4 bi = *(const float4*)&bias[f];
    float4 gi = *(const float4*)&g[f];
    float4 bei = *(const float4*)&be[f];
    acc.x = fmaxf((acc.x + bi.x) * gi.x * bns + bei.x, 0.0f);
    acc.y = fmaxf((acc.y + bi.y) * gi.y * bns + bei.y, 0.0f);
    acc.z = fmaxf((acc.z + bi.z) * gi.z * bns + bei.z, 0.0f);
    acc.w = fmaxf((acc.w + bi.w) * gi.w * bns + bei.w, 0.0f);
  }
  *(uint2*)&hout[(size_t)c * 256 + f] = pack_bf4(acc);
}

// D=128 bf16: two nodes per wave (half-wave x 4 feats, 8B/lane).
// EPI 0: plain bf16 store. EPI 2: +bias, log_softmax -> fp32 out.
template <int EPI>
__global__ __launch_bounds__(256) void agg128_kernel(
    const uint16_t* __restrict__ hin, void* __restrict__ hout_,
    const int* __restrict__ off, const uint2* __restrict__ csr,
    const float* __restrict__ dinv,
    const float* __restrict__ bias, int n) {
  const int lane = threadIdx.x & 63;
  const int sub = lane & 31;
  const int hbase = lane & 32;
  const int c = blockIdx.x * 8 + (threadIdx.x >> 6) * 2 + (lane >> 5);
  const bool active = (c < n);
  const int f = sub * 4;

  int e0 = 0, e1 = 0;
  float4 acc = make_float4(0.f, 0.f, 0.f, 0.f);
  if (active) {
    e0 = off[c]; e1 = off[c + 1];
    float di = dinv[c];
    float s2 = di * di;
    float4 self = unpack_bf4(*(const uint2*)&hin[(size_t)c * 128 + f]);
    acc = make_float4(self.x * s2, self.y * s2, self.z * s2, self.w * s2);
  }
  int nch = (e1 - e0 + 31) >> 5;
  nch = max(nch, __shfl(nch, lane ^ 32));

  for (int ch = 0; ch < nch; ++ch) {
    int idx = e0 + ch * 32 + sub;
    int rs = 0; float rv = 0.0f;
    if (active && idx < e1) { uint2 ev = csr[idx]; rs = (int)ev.x; rv = __uint_as_float(ev.y); }
    int m = e1 - (e0 + ch * 32);
    m = m < 0 ? 0 : (m > 32 ? 32 : m);
    int mMax = max(m, __shfl(m, lane ^ 32));
    const int nG = (mMax + 3) >> 2;
    for (int gI = 0; gI < nG; ++gI) {
      int e_ = hbase + gI * 4;
      int s0 = __shfl(rs, e_);     float v0 = __shfl(rv, e_);
      int s1 = __shfl(rs, e_ + 1); float v1 = __shfl(rv, e_ + 1);
      int sB = __shfl(rs, e_ + 2); float v2 = __shfl(rv, e_ + 2);
      int s3 = __shfl(rs, e_ + 3); float v3 = __shfl(rv, e_ + 3);
      float4 h0 = unpack_bf4(*(const uint2*)&hin[(size_t)s0 * 128 + f]);
      float4 h1 = unpack_bf4(*(const uint2*)&hin[(size_t)s1 * 128 + f]);
      float4 h2 = unpack_bf4(*(const uint2*)&hin[(size_t)sB * 128 + f]);
      float4 h3 = unpack_bf4(*(const uint2*)&hin[(size_t)s3 * 128 + f]);
      acc.x += v0 * h0.x + v1 * h1.x + v2 * h2.x + v3 * h3.x;
      acc.y += v0 * h0.y + v1 * h1.y + v2 * h2.y + v3 * h3.y;
      acc.z += v0 * h0.z + v1 * h1.z + v2 * h2.z + v3 * h3.z;
      acc.w += v0 * h0.w + v1 * h1.w + v2 * h2.w + v3 * h3.w;
    }
  }

  if (EPI == 0) {
    uint16_t* hout = (uint16_t*)hout_;
    if (active) *(uint2*)&hout[(size_t)c * 128 + f] = pack_bf4(acc);
  } else {
    float* hout = (float*)hout_;
    float4 bi = active ? *(const float4*)&bias[f] : make_float4(0.f, 0.f, 0.f, 0.f);
    float tx = acc.x + bi.x, ty = acc.y + bi.y, tz = acc.z + bi.z, tw = acc.w + bi.w;
    float mx = fmaxf(fmaxf(tx, ty), fmaxf(tz, tw));
#pragma unroll
    for (int s = 1; s < 32; s <<= 1) mx = fmaxf(mx, __shfl_xor(mx, s, 64));
    float ex = expf(tx - mx) + expf(ty - mx) + expf(tz - mx) + expf(tw - mx);
#pragma unroll
    for (int s = 1; s < 32; s <<= 1) ex += __shfl_xor(ex, s, 64);
    float lse = logf(ex) + mx;
    if (active) {
      float4 res = make_float4(tx - lse, ty - lse, tz - lse, tw - lse);
      *(float4*)&hout[(size_t)c * 128 + f] = res;
    }
  }
}

// ---------------------------------------------------------------- MFMA GEMM
// B-stationary: wave holds B-frags for its col group across all K in registers,
// streams 16-row A-tiles with depth-2 prefetch; 4 waves/block share A rows.
template <int K, int NC, int EPI>
__global__ __launch_bounds__(256) void mfma_gemm_kernel(
    const uint16_t* __restrict__ A, const uint16_t* __restrict__ WT,
    uint16_t* __restrict__ Cb, int M, int tpb,
    const float* __restrict__ bias, const float* __restrict__ g,
    const float* __restrict__ be) {
  constexpr int CW = NC / 4;
  constexpr int NT = CW / 16;
  constexpr int KS = K / 32;
  const int lane = threadIdx.x & 63;
  const int wave = threadIdx.x >> 6;
  const int quad = lane >> 4;
  const int l16 = lane & 15;
  const int col0 = wave * CW;

  const int tiles = (M + 15) >> 4;
  int t0 = blockIdx.x * tpb;
  if (t0 >= tiles) return;
  int t1 = min(t0 + tpb, tiles);

  v8bf b[KS][NT];
#pragma unroll
  for (int ks = 0; ks < KS; ++ks)
#pragma unroll
    for (int nt = 0; nt < NT; ++nt)
      b[ks][nt] = *(const v8bf*)(WT + (size_t)(col0 + nt * 16 + l16) * K +
                                 ks * 32 + quad * 8);

  float sc[NT], o1[NT], o2[NT];
  if (EPI == 1) {
    const float bns = rsqrtf(1.0f + GCN_BN_EPS);
#pragma unroll
    for (int nt = 0; nt < NT; ++nt) {
      int col = col0 + nt * 16 + l16;
      sc[nt] = g[col] * bns; o1[nt] = bias[col]; o2[nt] = be[col];
    }
  }

  v8bf a[KS], an[KS];
  {
    int arow = min(t0 * 16 + l16, M - 1);
    const uint16_t* Ap = A + (size_t)arow * K + quad * 8;
#pragma unroll
    for (int ks = 0; ks < KS; ++ks) a[ks] = *(const v8bf*)(Ap + ks * 32);
  }
  for (int t = t0; t < t1; ++t) {
    if (t + 1 < t1) {
      int arow = min((t + 1) * 16 + l16, M - 1);
      const uint16_t* Ap = A + (size_t)arow * K + quad * 8;
#pragma unroll
      for (int ks = 0; ks < KS; ++ks) an[ks] = *(const v8bf*)(Ap + ks * 32);
    }
    v4f acc[NT];
#pragma unroll
    for (int nt = 0; nt < NT; ++nt) acc[nt] = (v4f){0.f, 0.f, 0.f, 0.f};
#pragma unroll
    for (int ks = 0; ks < KS; ++ks)
#pragma unroll
      for (int nt = 0; nt < NT; ++nt)
        acc[nt] = __builtin_amdgcn_mfma_f32_16x16x32_bf16(a[ks], b[ks][nt],
                                                          acc[nt], 0, 0, 0);
    const int row0 = t * 16 + quad * 4;
#pragma unroll
    for (int nt = 0; nt < NT; ++nt) {
      const int col = col0 + nt * 16 + l16;
#pragma unroll
      for (int r = 0; r < 4; ++r) {
        int row = row0 + r;
        if (row < M) {
          float v = acc[nt][r];
          if (EPI == 1) v = fmaxf((v + o1[nt]) * sc[nt] + o2[nt], 0.0f);
          Cb[(size_t)row * NC + col] = f2bf(v);
        }
      }
    }
#pragma unroll
    for (int ks = 0; ks < KS; ++ks) a[ks] = an[ks];
  }
}

// ---------------------------------------------------------------- launch

static inline char* carve(char*& p, size_t bytes) {
  char* r = p;
  p += (bytes + 255) & ~(size_t)255;
  return r;
}

extern "C" void kernel_launch(void* const* d_in, const int* in_sizes, int n_in,
                              void* d_out, int out_size, void* d_ws, size_t ws_size,
                              hipStream_t stream) {
  const int N = in_sizes[0] / 128;
  const int E = in_sizes[2];

  const float* x  = (const float*)d_in[0];
  const int*   ei = (const int*)d_in[1];
  const float* ew = (const float*)d_in[2];
  const float* W0 = (const float*)d_in[3];
  const float* b0 = (const float*)d_in[4];
  const float* W1 = (const float*)d_in[5];
  const float* b1 = (const float*)d_in[6];
  const float* Wl = (const float*)d_in[7];
  const float* bl = (const float*)d_in[8];
  const float* g0 = (const float*)d_in[9];
  const float* be0 = (const float*)d_in[10];
  const float* g1 = (const float*)d_in[11];
  const float* be1 = (const float*)d_in[12];
  float* out = (float*)d_out;

  char* p = (char*)d_ws;
  float*    dinv    = (float*)carve(p, (size_t)N * 4);
  int*      cnt     = (int*)carve(p, (size_t)N * 4);
  int*      off     = (int*)carve(p, (size_t)(N + 1) * 4);
  int*      flag    = (int*)carve(p, 256);
  int*      bsum    = (int*)carve(p, 1024 * 4);
  int*      col_    = (int*)carve(p, (size_t)E * 4);
  uint2*    pk      = (uint2*)carve(p, (size_t)E * 8);
  uint2*    csr     = (uint2*)carve(p, (size_t)E * 8);
  int*      hist    = (int*)carve(p, (size_t)NB_CHUNK * N * 4);  // becomes base
  uint16_t* xb16    = (uint16_t*)carve(p, (size_t)N * 128 * 2);
  uint16_t* bufR    = (uint16_t*)carve(p, (size_t)N * 128 * 2);
  uint16_t* bufP    = (uint16_t*)carve(p, (size_t)N * 256 * 2);
  uint16_t* bufQ    = (uint16_t*)carve(p, (size_t)N * 256 * 2);
  uint16_t* W0t     = (uint16_t*)carve(p, (size_t)128 * 256 * 2);
  uint16_t* W1t     = (uint16_t*)carve(p, (size_t)256 * 256 * 2);
  uint16_t* Wlt     = (uint16_t*)carve(p, (size_t)256 * 128 * 2);

  const int TB = 256;
  const int gN = (N + TB - 1) / TB;
  const int gE = (E + TB - 1) / TB;
  const int gW4 = (N + 3) / 4;
  const int gW8 = (N + 7) / 8;
  const int tiles = (N + 15) / 16;
  const int TPB = 4;
  const int gG = (tiles + TPB - 1) / TPB;
  const int npl = (N + NPART - 1) / NPART;
  const size_t ldsHist = (size_t)((npl + 1) / 2) * 4;  // 25KB
  const size_t ldsFill = (size_t)npl * 4;              // 50KB
  const dim3 gHF(NB_CHUNK, NPART);

  // CSC build (zero global atomics, partitioned for occupancy)
  detect_kernel<<<1, 64, 0, stream>>>(ei, flag);
  decode_kernel<<<gE, TB, 0, stream>>>(ei, ew, flag, col_, pk, E);
  hist_kernel<<<gHF, TB, ldsHist, stream>>>(col_, hist, E, N);
  scan1_kernel<<<gN, TB, 0, stream>>>(hist, cnt, bsum, N);
  scan2_kernel<<<1, 1024, 0, stream>>>(bsum, gN, off, N, E);
  scan3_kernel<<<gN, TB, 0, stream>>>(cnt, bsum, off, N);
  base_kernel<<<gN, TB, 0, stream>>>(off, hist, N);
  fill_kernel<<<gHF, TB, ldsFill, stream>>>(col_, pk, hist, csr, E, N);
  degdinv_kernel<<<gN, TB, 0, stream>>>(off, csr, dinv, N);
  val_kernel<<<gN, TB, 0, stream>>>(off, csr, dinv, N);

  // conversions
  conv_x_kernel<<<(N * 32 + TB - 1) / TB, TB, 0, stream>>>(x, xb16, N * 32);
  conv_wt_kernel<<<(128 * 256 + TB - 1) / TB, TB, 0, stream>>>(W0, W0t, 128, 256);
  conv_wt_kernel<<<(256 * 256 + TB - 1) / TB, TB, 0, stream>>>(W1, W1t, 256, 256);
  conv_wt_kernel<<<(256 * 128 + TB - 1) / TB, TB, 0, stream>>>(Wl, Wlt, 256, 128);

  // layer 0: agg(xb16,128) -> bufR; MFMA GEMM0 +BN0+ReLU -> bufP[N,256]
  agg128_kernel<0><<<gW8, 256, 0, stream>>>(xb16, bufR, off, csr, dinv, nullptr, N);
  mfma_gemm_kernel<128, 256, 1><<<gG, 256, 0, stream>>>(bufR, W0t, bufP, N, TPB,
                                                        b0, g0, be0);
  // layer 1: GEMM1 -> bufQ; agg256 +b1+BN1+ReLU -> bufP
  mfma_gemm_kernel<256, 256, 0><<<gG, 256, 0, stream>>>(bufP, W1t, bufQ, N, TPB,
                                                        nullptr, nullptr, nullptr);
  agg256_kernel<1><<<gW4, 256, 0, stream>>>(bufQ, bufP, off, csr, dinv,
                                            b1, g1, be1, N);
  // layer 2: GEMM2 -> bufR; agg128 +bl+log_softmax -> out (fp32)
  mfma_gemm_kernel<256, 128, 0><<<gG, 256, 0, stream>>>(bufP, Wlt, bufR, N, TPB,
                                                        nullptr, nullptr, nullptr);
  agg128_kernel<2><<<gW8, 256, 0, stream>>>(bufR, out, off, csr, dinv, bl, N);
}